// Round 16
// baseline (157.135 us; speedup 1.0000x reference)
//
#include <hip/hip_runtime.h>
#include <stdint.h>

#define B_ 4
#define C_ 256
#define N_ 4096
#define L2E 1.4426950408889634f

typedef unsigned short u16;
typedef unsigned int u32;
typedef float f32x4 __attribute__((ext_vector_type(4)));
typedef __bf16 bf16x8 __attribute__((ext_vector_type(8)));

union U16x8 { uint4 q; bf16x8 v; u16 u[8]; __bf16 h[8]; };
union BF2 { u32 w; __bf16 h[2]; };

__device__ __forceinline__ bf16x8 ld_bf8(const u16* p) {
  U16x8 t; t.q = *(const uint4*)p; return t.v;
}
__device__ __forceinline__ f32x4 mfma16(bf16x8 a, bf16x8 b, f32x4 c) {
  return __builtin_amdgcn_mfma_f32_16x16x32_bf16(a, b, c, 0, 0, 0);
}
// raw barrier: LDS drained, global loads stay in flight (no vmcnt(0) drain)
#define BAR() do { asm volatile("s_waitcnt lgkmcnt(0)" ::: "memory"); \
                   __builtin_amdgcn_s_barrier(); } while (0)

// Fragment-major layouts (all hot loads are ptr + lane*16B, 1 segment/instr):
//   qfm/kfm: [b][chunk16 = n>>4][lane64][8 u16]   (lane = (n&15) + kgroup*16)
//   vq:      [b][chunk32 = n>>5][cfrag = c>>4][lane64][8 u16]
//   wvf/wtf: [(ocfrag*8 + kk)*64 + lane][8 u16]   (lane = (oc&15) + ((c>>3)&3)*16, j = c&7)

// ---------------- K-xt: x -> x_t bf16 [b][n][c]; + weight prep (fragment-major) ----------------
__global__ __launch_bounds__(256) void k_xt(const float* __restrict__ x, u16* __restrict__ xt,
                                            const float* __restrict__ vw, const float* __restrict__ tw,
                                            const float* __restrict__ qkw,
                                            u16* __restrict__ wvf, u16* __restrict__ wtf, float* __restrict__ wqkt) {
  int bid = blockIdx.x;
  if (bid < 64) {
    int i = bid * 256 + threadIdx.x;
    for (int idx = i; idx < C_ * C_; idx += 16384) {
      int oc = idx >> 8, c = idx & 255;
      int dst = (((oc >> 4) * 8 + (c >> 5)) * 64 + (oc & 15) + (((c >> 3) & 3) << 4)) * 8 + (c & 7);
      BF2 a2, b2; a2.h[0] = (__bf16)vw[idx]; b2.h[0] = (__bf16)tw[idx];
      wvf[dst] = (u16)(a2.w & 0xFFFF);
      wtf[dst] = (u16)(b2.w & 0xFFFF);
    }
    for (int idx = i; idx < 32 * C_; idx += 16384) {
      int c = idx >> 8, cin = idx & 255;
      wqkt[cin * 32 + c] = qkw[idx];         // transposed, fp32 (exponent-accuracy path)
    }
  }
  int cb = bid & 3, nt = (bid >> 2) & 63, b = bid >> 8;
  __shared__ u16 tile[64][66];
  int t = threadIdx.x, nl = t & 63, cg = t >> 6;
  const float* xp = x + ((size_t)b * C_ + cb * 64) * N_ + nt * 64;
  #pragma unroll
  for (int cc = 0; cc < 16; ++cc) {
    int c = cg * 16 + cc;
    BF2 v; v.h[0] = (__bf16)xp[(size_t)c * N_ + nl];
    tile[c][nl] = (u16)(v.w & 0xFFFF);
  }
  __syncthreads();
  u16* op = xt + ((size_t)b * N_ + nt * 64) * C_ + cb * 64;
  #pragma unroll
  for (int nn = 0; nn < 16; ++nn) {
    int n2 = cg * 16 + nn;
    op[(size_t)n2 * C_ + nl] = tile[nl][n2];
  }
}

// ---------------- K-qk: fp32 GEMM + bn1/bn2 + relu -> q',k' fragment-major ----------------
__global__ __launch_bounds__(256) void k_qk(
    const float* __restrict__ x, const float* __restrict__ wqkt,
    const float* __restrict__ bn1s, const float* __restrict__ bn1b,
    const float* __restrict__ bn2s, const float* __restrict__ bn2b,
    u16* __restrict__ qfm, u16* __restrict__ kfm,
    float* __restrict__ qsg, float* __restrict__ ksg) {
  int bid = blockIdx.x;
  bid = (bid & 7) * 32 + (bid >> 3);
  int nt = bid & 63, b = bid >> 6;
  int t = threadIdx.x;
  int nl = t & 63;
  int qg = __builtin_amdgcn_readfirstlane(t >> 6);
  int n = nt * 64 + nl;

  __shared__ float red[4][64][33];
  __shared__ float qsum[4][64], ksum[4][64];

  float acc[32];
  #pragma unroll
  for (int c = 0; c < 32; ++c) acc[c] = 0.f;

  const float* xp = x + ((size_t)b * C_ + qg * 64) * N_ + n;
  const float* wp = wqkt + qg * 64 * 32;
  for (int i = 0; i < 64; ++i) {
    float xvv = xp[(size_t)i * N_];
    const float* wr = wp + i * 32;
    #pragma unroll
    for (int c = 0; c < 32; ++c) acc[c] = fmaf(wr[c], xvv, acc[c]);
  }
  #pragma unroll
  for (int c = 0; c < 32; ++c) red[qg][nl][c] = acc[c];
  __syncthreads();

  float pqs = 0.f, pks = 0.f;
  U16x8 tq, tk;
  #pragma unroll
  for (int i2 = 0; i2 < 8; ++i2) {
    int c = qg * 8 + i2;
    float s = red[0][nl][c] + red[1][nl][c] + red[2][nl][c] + red[3][nl][c];
    float fq = fmaxf(fmaf(s, bn1s[c], bn1b[c]), 0.f);
    float fk = fmaxf(fmaf(s, bn2s[c], bn2b[c]), 0.f);
    pqs += fq; pks += fk;
    tq.h[i2] = (__bf16)fq; tk.h[i2] = (__bf16)fk;
  }
  size_t fbase = (((size_t)b * 256 + (n >> 4)) * 64 + (n & 15) + qg * 16) * 8;
  *(uint4*)(qfm + fbase) = tq.q;
  *(uint4*)(kfm + fbase) = tk.q;

  qsum[qg][nl] = pqs; ksum[qg][nl] = pks;
  __syncthreads();
  if (t < 64) {
    int nn2 = nt * 64 + t;
    qsg[b * N_ + nn2] = (qsum[0][t] + qsum[1][t] + qsum[2][t] + qsum[3][t]) * L2E;
    ksg[b * N_ + nn2] = ksum[0][t] + ksum[1][t] + ksum[2][t] + ksum[3][t];
  }
}

// ---------------- K-gemm256: de-scattered — frag-major W + LDS-staged act ----------------
// MODE 0: v-conv -> vq fragment-major (LDS-coalesced dump)
// MODE 1: trans-conv + residual -> out fp32
template<int MODE>
__global__ __launch_bounds__(256) void k_gemm256(
    const u16* __restrict__ Wf, const u16* __restrict__ act,
    const float* __restrict__ bias, const float* __restrict__ bns, const float* __restrict__ bnb,
    const float* __restrict__ xres, u16* __restrict__ outb, float* __restrict__ outf) {
  int bid = blockIdx.x;
  bid = (bid & 7) * 64 + (bid >> 3);
  int nt = bid & 127, b = bid >> 7;
  int n0 = nt * 32;
  int t = threadIdx.x;
  int w = t >> 6, l = t & 63, lr = l & 15, lg = l >> 4;

  // atile (main loop) aliases fbuf (MODE-0 epilogue) — barrier-separated
  __shared__ __align__(16) char gsm[32 * 264 * 2];   // 16.9 KB
  u16 (*atile)[264] = (u16(*)[264])gsm;              // +8 u16 pad: b128 reads at bank floor
  u16* fbuf = (u16*)gsm;

  // stage act tile [32 n][256 c] coalesced (rows contiguous in c)
  const u16* asrc = act + ((size_t)b * N_ + n0) * C_;
  #pragma unroll
  for (int rep = 0; rep < 4; ++rep) {
    int idx8 = rep * 256 + t, row = idx8 >> 5, col8 = idx8 & 31;
    *(uint4*)&atile[row][col8 * 8] = *(const uint4*)(asrc + (size_t)row * C_ + col8 * 8);
  }
  __syncthreads();

  f32x4 acc[4][2];
  #pragma unroll
  for (int ot = 0; ot < 4; ++ot)
    #pragma unroll
    for (int ns = 0; ns < 2; ++ns) acc[ot][ns] = f32x4{0.f, 0.f, 0.f, 0.f};

  for (int kk = 0; kk < 8; ++kk) {
    bf16x8 bf[2];
    #pragma unroll
    for (int ns = 0; ns < 2; ++ns)
      bf[ns] = ld_bf8(&atile[ns * 16 + lr][kk * 32 + lg * 8]);
    #pragma unroll
    for (int ot = 0; ot < 4; ++ot) {
      bf16x8 af = ld_bf8(Wf + (size_t)((w * 4 + ot) * 8 + kk) * 512 + l * 8);  // 1 segment
      #pragma unroll
      for (int ns = 0; ns < 2; ++ns) acc[ot][ns] = mfma16(af, bf[ns], acc[ot][ns]);
    }
  }
  if (MODE == 0) __syncthreads();   // atile reads drained before fbuf alias writes

  #pragma unroll
  for (int ot = 0; ot < 4; ++ot) {
    #pragma unroll
    for (int r = 0; r < 4; ++r) {
      int oc = w * 64 + ot * 16 + lg * 4 + r;
      float sO = bns[oc], bO = bnb[oc], biO = bias[oc];
      #pragma unroll
      for (int ns = 0; ns < 2; ++ns) {
        float val = fmaxf(fmaf(acc[ot][ns][r] + biO, sO, bO), 0.f);
        if (MODE == 0) {
          int u16off = (lg * 4 + r) * 8 + (lr >> 2) * 128 + ns * 4 + (lr & 3);
          BF2 v; v.h[0] = (__bf16)val;
          fbuf[(w * 4 + ot) * 512 + u16off] = (u16)(v.w & 0xFFFF);
        } else {
          int nn = ns * 16 + lr;
          size_t idx = ((size_t)b * C_ + oc) * N_ + n0 + nn;
          outf[idx] = xres[idx] + val;
        }
      }
    }
  }
  if (MODE == 0) {
    __syncthreads();
    #pragma unroll
    for (int rep = 0; rep < 4; ++rep) {
      int f = rep * 4 + (t >> 6);
      size_t dst = (((size_t)b * 128 + nt) * 16 + f) * 512 + (size_t)(t & 63) * 8;
      *(uint4*)(outb + dst) = *(const uint4*)&fbuf[f * 512 + (t & 63) * 8];
    }
  }
}

// ---------------- K-phaseA: fused row stat rmg = max' + log2(sum') ----------------
__global__ __launch_bounds__(512) void k_phaseA(
    const u16* __restrict__ qfm, const u16* __restrict__ kfm,
    const float* __restrict__ qsg, const float* __restrict__ ksg,
    float* __restrict__ rmg) {
  int bid = blockIdx.x;
  bid = (bid & 7) * 64 + (bid >> 3);
  int nt = bid & 127, b = bid >> 7;
  int bN = b * N_;
  int t = threadIdx.x;
  int w = t >> 6, l = t & 63, lr = l & 15, lg = l >> 4;
  int nsub = w & 1, mq = w >> 1;
  int nrow0 = nt * 32 + nsub * 16;

  __shared__ float pM[4][32], pS[4][32];

  const u16* qf_b = qfm + (size_t)b * 131072;
  const u16* kf_b = kfm + (size_t)b * 131072;

  bf16x8 qf = ld_bf8(qf_b + (size_t)(nrow0 >> 4) * 512 + l * 8);
  f32x4 qsv = *(const f32x4*)(qsg + bN + nrow0 + lg * 4);   // already *L2E

  float Mv[4], Sv[4];
  #pragma unroll
  for (int r = 0; r < 4; ++r) { Mv[r] = -3e38f; Sv[r] = 0.f; }

  int mbase = mq * 1024;
  for (int ms = 0; ms < 16; ++ms) {
    float ev[4][4];
    #pragma unroll
    for (int mt2 = 0; mt2 < 4; ++mt2) {
      int m0 = mbase + ms * 64 + mt2 * 16;
      bf16x8 kf = ld_bf8(kf_b + (size_t)(m0 >> 4) * 512 + l * 8);
      f32x4 e = mfma16(qf, kf, f32x4{0.f, 0.f, 0.f, 0.f});
      float ksv = ksg[bN + m0 + lr];
      #pragma unroll
      for (int r = 0; r < 4; ++r) ev[mt2][r] = fmaf(e[r], L2E, -qsv[r] * ksv);  // scaled e'
    }
    #pragma unroll
    for (int r = 0; r < 4; ++r) {
      float t0 = fmaxf(fmaxf(ev[0][r], ev[1][r]), fmaxf(ev[2][r], ev[3][r]));
      float Mn = fmaxf(Mv[r], t0);
      Sv[r] = Sv[r] * __builtin_amdgcn_exp2f(Mv[r] - Mn)
            + __builtin_amdgcn_exp2f(ev[0][r] - Mn)
            + __builtin_amdgcn_exp2f(ev[1][r] - Mn)
            + __builtin_amdgcn_exp2f(ev[2][r] - Mn)
            + __builtin_amdgcn_exp2f(ev[3][r] - Mn);
      Mv[r] = Mn;
    }
  }
  #pragma unroll
  for (int off = 1; off < 16; off <<= 1) {
    #pragma unroll
    for (int r = 0; r < 4; ++r) {
      float Mo = __shfl_xor(Mv[r], off);
      float So = __shfl_xor(Sv[r], off);
      float Mn = fmaxf(Mv[r], Mo);
      Sv[r] = Sv[r] * __builtin_amdgcn_exp2f(Mv[r] - Mn)
            + So   * __builtin_amdgcn_exp2f(Mo   - Mn);
      Mv[r] = Mn;
    }
  }
  if (lr == 0) {
    #pragma unroll
    for (int r = 0; r < 4; ++r) {
      pM[mq][nsub * 16 + lg * 4 + r] = Mv[r];
      pS[mq][nsub * 16 + lg * 4 + r] = Sv[r];
    }
  }
  __syncthreads();
  if (t < 32) {
    float M = fmaxf(fmaxf(pM[0][t], pM[1][t]), fmaxf(pM[2][t], pM[3][t]));
    float S = pS[0][t] * __builtin_amdgcn_exp2f(pM[0][t] - M)
            + pS[1][t] * __builtin_amdgcn_exp2f(pM[1][t] - M)
            + pS[2][t] * __builtin_amdgcn_exp2f(pM[2][t] - M)
            + pS[3][t] * __builtin_amdgcn_exp2f(pM[3][t] - M);
    rmg[bN + nt * 32 + t] = M + __builtin_amdgcn_logf(S);   // v_log_f32 = log2
  }
}

// ---------------- K-phaseB: producer-consumer flash PV (R11 champion + T5 setprio) ----------------
// 512 blocks (b, mt128) x 512 thr; 8 waves = (cq4, nh2); wave = m32 x c64 x n-half.
// LDS aliased to 33.8 KB; launch_bounds(512,4) -> VGPR cap 128 (natural 64, R9/R11-proven).
// T5: s_setprio(1) around the consume MFMA cluster — biases CU scheduler toward
// MFMA-issuing waves while co-resident waves run the VALU-heavy produce phase.
__global__ __launch_bounds__(512, 4) void k_phaseB(
    const u16* __restrict__ qfm, const u16* __restrict__ kfm,
    const float* __restrict__ qsg, const float* __restrict__ ksg,
    const float* __restrict__ rmg,
    const u16* __restrict__ vq, const u16* __restrict__ xt,
    u16* __restrict__ diffb) {
  int bid = blockIdx.x;
  bid = (bid & 7) * 64 + (bid >> 3);       // XCD swizzle (512 wgs, bijective)
  int mt = bid & 127, b = bid >> 7;
  int m0 = mt * 32;
  int bN = b * N_;
  int t = threadIdx.x;
  int w = t >> 6, l = t & 63, lr = l & 15, lg = l >> 4;
  int cq = w & 3, nh = w >> 2;
  int c0 = cq * 64;

  // aliased region: pbuf[2][2][4][1024] u16 (32KB, loop) == accl[4][2048] f32 (32KB, epilogue)
  __shared__ __align__(16) char smem[33792];
  u16 (*pbuf)[2][4][1024] = (u16(*)[2][4][1024])smem;
  float (*accl)[2048] = (float(*)[2048])smem;
  float (*csl)[32] = (float(*)[32])(smem + 32768);   // [8][32]

  bf16x8 kf0 = ld_bf8(kfm + (size_t)b * 131072 + (size_t)(mt * 2) * 512 + l * 8);
  bf16x8 kf1 = ld_bf8(kfm + (size_t)b * 131072 + (size_t)(mt * 2 + 1) * 512 + l * 8);
  float ks0 = ksg[bN + m0 + lr];
  float ks1 = ksg[bN + m0 + 16 + lr];

  U16x8 onesu;
  #pragma unroll
  for (int i = 0; i < 8; ++i) onesu.u[i] = 0x3F80;   // bf16 1.0
  bf16x8 ones = onesu.v;

  const u16* qf_b = qfm + (size_t)b * 131072;
  const float* qsb = qsg + bN;
  const float* rmb = rmg + bN;
  const u16* vq_b = vq + (size_t)b * 1048576 + (size_t)(cq * 4) * 512 + (size_t)l * 8;

  f32x4 acc0[4], acc1[4];
  #pragma unroll
  for (int ct = 0; ct < 4; ++ct) {
    acc0[ct] = f32x4{0.f, 0.f, 0.f, 0.f};
    acc1[ct] = f32x4{0.f, 0.f, 0.f, 0.f};
  }
  f32x4 accs0 = f32x4{0.f, 0.f, 0.f, 0.f};
  f32x4 accs1 = f32x4{0.f, 0.f, 0.f, 0.f};

  auto produce = [&](int wd, int buf) {
    bf16x8 qf0 = ld_bf8(qf_b + (size_t)(wd * 2) * 512 + l * 8);
    bf16x8 qf1 = ld_bf8(qf_b + (size_t)(wd * 2 + 1) * 512 + l * 8);
    int nb = wd * 32;
    f32x4 qs0 = *(const f32x4*)(qsb + nb + lg * 4);
    f32x4 qs1 = *(const f32x4*)(qsb + nb + 16 + lg * 4);
    f32x4 rm0 = *(const f32x4*)(rmb + nb + lg * 4);
    f32x4 rm1 = *(const f32x4*)(rmb + nb + 16 + lg * 4);

    f32x4 e00 = mfma16(qf0, kf0, f32x4{0.f, 0.f, 0.f, 0.f});
    f32x4 e01 = mfma16(qf1, kf0, f32x4{0.f, 0.f, 0.f, 0.f});
    f32x4 e10 = mfma16(qf0, kf1, f32x4{0.f, 0.f, 0.f, 0.f});
    f32x4 e11 = mfma16(qf1, kf1, f32x4{0.f, 0.f, 0.f, 0.f});

    float p00[4], p01[4], p10[4], p11[4];
    #pragma unroll
    for (int r = 0; r < 4; ++r) {
      p00[r] = __builtin_amdgcn_exp2f(fmaf(qs0[r], -ks0, fmaf(e00[r], L2E, -rm0[r])));
      p01[r] = __builtin_amdgcn_exp2f(fmaf(qs1[r], -ks0, fmaf(e01[r], L2E, -rm1[r])));
      p10[r] = __builtin_amdgcn_exp2f(fmaf(qs0[r], -ks1, fmaf(e10[r], L2E, -rm0[r])));
      p11[r] = __builtin_amdgcn_exp2f(fmaf(qs1[r], -ks1, fmaf(e11[r], L2E, -rm1[r])));
    }
    U16x8 pb0, pb1;
    #pragma unroll
    for (int r = 0; r < 4; ++r) {
      pb0.h[r] = (__bf16)p00[r]; pb0.h[4 + r] = (__bf16)p01[r];
      pb1.h[r] = (__bf16)p10[r]; pb1.h[4 + r] = (__bf16)p11[r];
    }
    accs0 = mfma16(ones, pb0.v, accs0);    // colsum once per window (matrix pipe)
    accs1 = mfma16(ones, pb1.v, accs1);
    u16* dst = &pbuf[nh][buf][cq][0];
    *(uint4*)&dst[l * 8] = pb0.q;
    *(uint4*)&dst[512 + l * 8] = pb1.q;
  };

  int wbase = nh * 64;
  produce(wbase + cq, 0);
  BAR();

  for (int g = 0; g < 16; ++g) {
    if (g < 15) produce(wbase + (g + 1) * 4 + cq, (g + 1) & 1);
    int gbuf = g & 1;
    __builtin_amdgcn_s_setprio(1);         // T5: favor the MFMA-heavy consume phase
    #pragma unroll
    for (int j = 0; j < 4; ++j) {
      int wd = wbase + g * 4 + j;
      const u16* src = &pbuf[nh][gbuf][j][0];
      U16x8 pb0, pb1;
      pb0.q = *(const uint4*)&src[l * 8];
      pb1.q = *(const uint4*)&src[512 + l * 8];
      const u16* vp = vq_b + (size_t)wd * 8192;
      U16x8 v0, v1, v2, v3;
      v0.q = *(const uint4*)(vp);
      v1.q = *(const uint4*)(vp + 512);
      v2.q = *(const uint4*)(vp + 1024);
      v3.q = *(const uint4*)(vp + 1536);
      acc0[0] = mfma16(v0.v, pb0.v, acc0[0]);
      acc1[0] = mfma16(v0.v, pb1.v, acc1[0]);
      acc0[1] = mfma16(v1.v, pb0.v, acc0[1]);
      acc1[1] = mfma16(v1.v, pb1.v, acc1[1]);
      acc0[2] = mfma16(v2.v, pb0.v, acc0[2]);
      acc1[2] = mfma16(v2.v, pb1.v, acc1[2]);
      acc0[3] = mfma16(v3.v, pb0.v, acc0[3]);
      acc1[3] = mfma16(v3.v, pb1.v, acc1[3]);
    }
    __builtin_amdgcn_s_setprio(0);
    BAR();   // produce(g+1) visible; consume(g) drained -> buf reusable at g+2; pbuf free after g=15
  }

  // colsum publish (each produced window counted once; sum all 8 waves)
  if (lg == 0) { csl[w][lr] = accs0[0]; csl[w][16 + lr] = accs1[0]; }
  // accl ALIASES pbuf: safe — final BAR drained every wave's last pbuf read
  if (nh == 1) {
    #pragma unroll
    for (int ct = 0; ct < 4; ++ct) {
      *(f32x4*)&accl[cq][(ct * 2 + 0) * 256 + l * 4] = acc0[ct];
      *(f32x4*)&accl[cq][(ct * 2 + 1) * 256 + l * 4] = acc1[ct];
    }
  }
  __syncthreads();
  if (nh == 0) {
    #pragma unroll
    for (int ct = 0; ct < 4; ++ct) {
      acc0[ct] += *(const f32x4*)&accl[cq][(ct * 2 + 0) * 256 + l * 4];
      acc1[ct] += *(const f32x4*)&accl[cq][(ct * 2 + 1) * 256 + l * 4];
    }
    float s0 = 0.f, s1 = 0.f;
    #pragma unroll
    for (int i = 0; i < 8; ++i) { s0 += csl[i][lr]; s1 += csl[i][16 + lr]; }
    float inv0 = __builtin_amdgcn_rcpf(1e-9f + s0);
    float inv1 = __builtin_amdgcn_rcpf(1e-9f + s1);

    // epilogue: diff = x - acc*inv, bf16 [b][n][c]
    #pragma unroll
    for (int ct = 0; ct < 4; ++ct) {
      {
        size_t base = ((size_t)(bN + m0 + lr)) * C_ + c0 + ct * 16 + lg * 4;
        uint2 xv2 = *(const uint2*)(xt + base);
        BF2 xa, xb; xa.w = xv2.x; xb.w = xv2.y;
        BF2 o0, o1;
        o0.h[0] = (__bf16)((float)xa.h[0] - acc0[ct][0] * inv0);
        o0.h[1] = (__bf16)((float)xa.h[1] - acc0[ct][1] * inv0);
        o1.h[0] = (__bf16)((float)xb.h[0] - acc0[ct][2] * inv0);
        o1.h[1] = (__bf16)((float)xb.h[1] - acc0[ct][3] * inv0);
        uint2 ov; ov.x = o0.w; ov.y = o1.w;
        *(uint2*)(diffb + base) = ov;
      }
      {
        size_t base = ((size_t)(bN + m0 + 16 + lr)) * C_ + c0 + ct * 16 + lg * 4;
        uint2 xv2 = *(const uint2*)(xt + base);
        BF2 xa, xb; xa.w = xv2.x; xb.w = xv2.y;
        BF2 o0, o1;
        o0.h[0] = (__bf16)((float)xa.h[0] - acc1[ct][0] * inv1);
        o0.h[1] = (__bf16)((float)xa.h[1] - acc1[ct][1] * inv1);
        o1.h[0] = (__bf16)((float)xb.h[0] - acc1[ct][2] * inv1);
        o1.h[1] = (__bf16)((float)xb.h[1] - acc1[ct][3] * inv1);
        uint2 ov; ov.x = o0.w; ov.y = o1.w;
        *(uint2*)(diffb + base) = ov;
      }
    }
  }
}

// ---------------- launch ----------------
extern "C" void kernel_launch(void* const* d_in, const int* in_sizes, int n_in,
                              void* d_out, int out_size, void* d_ws, size_t ws_size,
                              hipStream_t stream) {
  const float* x       = (const float*)d_in[0];
  const float* qk_w    = (const float*)d_in[1];
  const float* v_w     = (const float*)d_in[2];
  const float* v_b     = (const float*)d_in[3];
  const float* trans_w = (const float*)d_in[4];
  const float* trans_b = (const float*)d_in[5];
  const float* bn1s = (const float*)d_in[6];
  const float* bn1b = (const float*)d_in[7];
  const float* bn2s = (const float*)d_in[8];
  const float* bn2b = (const float*)d_in[9];
  const float* bn3s = (const float*)d_in[10];
  const float* bn3b = (const float*)d_in[11];
  const float* ans  = (const float*)d_in[12];
  const float* anb  = (const float*)d_in[13];
  float* out = (float*)d_out;
  char* ws = (char*)d_ws;

  if (ws_size < 27820032) return;

  u16*   xt    = (u16*)(ws + 0);          // [B][N][C] bf16   8 MB
  u16*   vq    = (u16*)(ws + 8388608);    // V fragment-major 8 MB
  u16*   diffb = (u16*)(ws + 16777216);   // [B][N][C] bf16   8 MB
  u16*   qfm   = (u16*)(ws + 25165824);   // q frags 1 MB
  u16*   kfm   = (u16*)(ws + 26214400);   // k frags 1 MB
  u16*   wvf   = (u16*)(ws + 27262976);   // v-weights fragment-major
  u16*   wtf   = (u16*)(ws + 27394048);   // t-weights fragment-major
  float* wqkt  = (float*)(ws + 27525120);
  float* qsg   = (float*)(ws + 27557888);
  float* ksg   = (float*)(ws + 27623424);
  float* rmg   = (float*)(ws + 27688960);

  k_xt<<<1024, 256, 0, stream>>>(x, xt, v_w, trans_w, qk_w, wvf, wtf, wqkt);
  k_qk<<<256, 256, 0, stream>>>(x, wqkt, bn1s, bn1b, bn2s, bn2b, qfm, kfm, qsg, ksg);
  k_gemm256<0><<<512, 256, 0, stream>>>(wvf, xt, v_b, bn3s, bn3b, nullptr, vq, nullptr);
  k_phaseA<<<512, 512, 0, stream>>>(qfm, kfm, qsg, ksg, rmg);
  k_phaseB<<<512, 512, 0, stream>>>(qfm, kfm, qsg, ksg, rmg, vq, xt, diffb);
  k_gemm256<1><<<512, 256, 0, stream>>>(wtf, diffb, trans_b, ans, anb, x, nullptr, out);
}

// Round 17
// 119.686 us; speedup vs baseline: 1.3129x; 1.3129x over previous
//
#include <hip/hip_runtime.h>
#include <stdint.h>

#define B_ 4
#define C_ 256
#define N_ 4096
#define L2E 1.4426950408889634f

typedef unsigned short u16;
typedef unsigned int u32;
typedef float f32x4 __attribute__((ext_vector_type(4)));
typedef __bf16 bf16x8 __attribute__((ext_vector_type(8)));

union U16x8 { uint4 q; bf16x8 v; u16 u[8]; __bf16 h[8]; };
union BF2 { u32 w; __bf16 h[2]; };

__device__ __forceinline__ bf16x8 ld_bf8(const u16* p) {
  U16x8 t; t.q = *(const uint4*)p; return t.v;
}
__device__ __forceinline__ f32x4 mfma16(bf16x8 a, bf16x8 b, f32x4 c) {
  return __builtin_amdgcn_mfma_f32_16x16x32_bf16(a, b, c, 0, 0, 0);
}
// raw barrier: LDS drained, global loads stay in flight (no vmcnt(0) drain)
#define BAR() do { asm volatile("s_waitcnt lgkmcnt(0)" ::: "memory"); \
                   __builtin_amdgcn_s_barrier(); } while (0)

// Fragment-major layouts (all hot loads are ptr + lane*16B, 1 segment/instr):
//   qfm/kfm: [b][chunk16 = n>>4][lane64][8 u16]   (lane = (n&15) + kgroup*16)
//   vq:      [b][chunk32 = n>>5][cfrag = c>>4][lane64][8 u16]
//   wvf/wtf: [(ocfrag*8 + kk)*64 + lane][8 u16]   (lane = (oc&15) + ((c>>3)&3)*16, j = c&7)

// ---------------- K-xt: x -> x_t bf16 [b][n][c]; + weight prep (fragment-major) ----------------
__global__ __launch_bounds__(256) void k_xt(const float* __restrict__ x, u16* __restrict__ xt,
                                            const float* __restrict__ vw, const float* __restrict__ tw,
                                            const float* __restrict__ qkw,
                                            u16* __restrict__ wvf, u16* __restrict__ wtf, float* __restrict__ wqkt) {
  int bid = blockIdx.x;
  if (bid < 64) {
    int i = bid * 256 + threadIdx.x;
    for (int idx = i; idx < C_ * C_; idx += 16384) {
      int oc = idx >> 8, c = idx & 255;
      int dst = (((oc >> 4) * 8 + (c >> 5)) * 64 + (oc & 15) + (((c >> 3) & 3) << 4)) * 8 + (c & 7);
      BF2 a2, b2; a2.h[0] = (__bf16)vw[idx]; b2.h[0] = (__bf16)tw[idx];
      wvf[dst] = (u16)(a2.w & 0xFFFF);
      wtf[dst] = (u16)(b2.w & 0xFFFF);
    }
    for (int idx = i; idx < 32 * C_; idx += 16384) {
      int c = idx >> 8, cin = idx & 255;
      wqkt[cin * 32 + c] = qkw[idx];         // transposed, fp32 (exponent-accuracy path)
    }
  }
  int cb = bid & 3, nt = (bid >> 2) & 63, b = bid >> 8;
  __shared__ u16 tile[64][66];
  int t = threadIdx.x, nl = t & 63, cg = t >> 6;
  const float* xp = x + ((size_t)b * C_ + cb * 64) * N_ + nt * 64;
  #pragma unroll
  for (int cc = 0; cc < 16; ++cc) {
    int c = cg * 16 + cc;
    BF2 v; v.h[0] = (__bf16)xp[(size_t)c * N_ + nl];
    tile[c][nl] = (u16)(v.w & 0xFFFF);
  }
  __syncthreads();
  u16* op = xt + ((size_t)b * N_ + nt * 64) * C_ + cb * 64;
  #pragma unroll
  for (int nn = 0; nn < 16; ++nn) {
    int n2 = cg * 16 + nn;
    op[(size_t)n2 * C_ + nl] = tile[nl][n2];
  }
}

// ---------------- K-qk: fp32 GEMM + bn1/bn2 + relu -> q',k' fragment-major ----------------
__global__ __launch_bounds__(256) void k_qk(
    const float* __restrict__ x, const float* __restrict__ wqkt,
    const float* __restrict__ bn1s, const float* __restrict__ bn1b,
    const float* __restrict__ bn2s, const float* __restrict__ bn2b,
    u16* __restrict__ qfm, u16* __restrict__ kfm,
    float* __restrict__ qsg, float* __restrict__ ksg) {
  int bid = blockIdx.x;
  bid = (bid & 7) * 32 + (bid >> 3);
  int nt = bid & 63, b = bid >> 6;
  int t = threadIdx.x;
  int nl = t & 63;
  int qg = __builtin_amdgcn_readfirstlane(t >> 6);
  int n = nt * 64 + nl;

  __shared__ float red[4][64][33];
  __shared__ float qsum[4][64], ksum[4][64];

  float acc[32];
  #pragma unroll
  for (int c = 0; c < 32; ++c) acc[c] = 0.f;

  const float* xp = x + ((size_t)b * C_ + qg * 64) * N_ + n;
  const float* wp = wqkt + qg * 64 * 32;
  for (int i = 0; i < 64; ++i) {
    float xvv = xp[(size_t)i * N_];
    const float* wr = wp + i * 32;
    #pragma unroll
    for (int c = 0; c < 32; ++c) acc[c] = fmaf(wr[c], xvv, acc[c]);
  }
  #pragma unroll
  for (int c = 0; c < 32; ++c) red[qg][nl][c] = acc[c];
  __syncthreads();

  float pqs = 0.f, pks = 0.f;
  U16x8 tq, tk;
  #pragma unroll
  for (int i2 = 0; i2 < 8; ++i2) {
    int c = qg * 8 + i2;
    float s = red[0][nl][c] + red[1][nl][c] + red[2][nl][c] + red[3][nl][c];
    float fq = fmaxf(fmaf(s, bn1s[c], bn1b[c]), 0.f);
    float fk = fmaxf(fmaf(s, bn2s[c], bn2b[c]), 0.f);
    pqs += fq; pks += fk;
    tq.h[i2] = (__bf16)fq; tk.h[i2] = (__bf16)fk;
  }
  size_t fbase = (((size_t)b * 256 + (n >> 4)) * 64 + (n & 15) + qg * 16) * 8;
  *(uint4*)(qfm + fbase) = tq.q;
  *(uint4*)(kfm + fbase) = tk.q;

  qsum[qg][nl] = pqs; ksum[qg][nl] = pks;
  __syncthreads();
  if (t < 64) {
    int nn2 = nt * 64 + t;
    qsg[b * N_ + nn2] = (qsum[0][t] + qsum[1][t] + qsum[2][t] + qsum[3][t]) * L2E;
    ksg[b * N_ + nn2] = ksum[0][t] + ksum[1][t] + ksum[2][t] + ksum[3][t];
  }
}

// ---------------- K-gemm256: de-scattered — frag-major W + LDS-staged act ----------------
// MODE 0: v-conv -> vq fragment-major (LDS-coalesced dump)
// MODE 1: trans-conv + residual -> out fp32
template<int MODE>
__global__ __launch_bounds__(256) void k_gemm256(
    const u16* __restrict__ Wf, const u16* __restrict__ act,
    const float* __restrict__ bias, const float* __restrict__ bns, const float* __restrict__ bnb,
    const float* __restrict__ xres, u16* __restrict__ outb, float* __restrict__ outf) {
  int bid = blockIdx.x;
  bid = (bid & 7) * 64 + (bid >> 3);
  int nt = bid & 127, b = bid >> 7;
  int n0 = nt * 32;
  int t = threadIdx.x;
  int w = t >> 6, l = t & 63, lr = l & 15, lg = l >> 4;

  // atile (main loop) aliases fbuf (MODE-0 epilogue) — barrier-separated
  __shared__ __align__(16) char gsm[32 * 264 * 2];   // 16.9 KB
  u16 (*atile)[264] = (u16(*)[264])gsm;              // +8 u16 pad: b128 reads at bank floor
  u16* fbuf = (u16*)gsm;

  // stage act tile [32 n][256 c] coalesced (rows contiguous in c)
  const u16* asrc = act + ((size_t)b * N_ + n0) * C_;
  #pragma unroll
  for (int rep = 0; rep < 4; ++rep) {
    int idx8 = rep * 256 + t, row = idx8 >> 5, col8 = idx8 & 31;
    *(uint4*)&atile[row][col8 * 8] = *(const uint4*)(asrc + (size_t)row * C_ + col8 * 8);
  }
  __syncthreads();

  f32x4 acc[4][2];
  #pragma unroll
  for (int ot = 0; ot < 4; ++ot)
    #pragma unroll
    for (int ns = 0; ns < 2; ++ns) acc[ot][ns] = f32x4{0.f, 0.f, 0.f, 0.f};

  for (int kk = 0; kk < 8; ++kk) {
    bf16x8 bf[2];
    #pragma unroll
    for (int ns = 0; ns < 2; ++ns)
      bf[ns] = ld_bf8(&atile[ns * 16 + lr][kk * 32 + lg * 8]);
    #pragma unroll
    for (int ot = 0; ot < 4; ++ot) {
      bf16x8 af = ld_bf8(Wf + (size_t)((w * 4 + ot) * 8 + kk) * 512 + l * 8);  // 1 segment
      #pragma unroll
      for (int ns = 0; ns < 2; ++ns) acc[ot][ns] = mfma16(af, bf[ns], acc[ot][ns]);
    }
  }
  if (MODE == 0) __syncthreads();   // atile reads drained before fbuf alias writes

  #pragma unroll
  for (int ot = 0; ot < 4; ++ot) {
    #pragma unroll
    for (int r = 0; r < 4; ++r) {
      int oc = w * 64 + ot * 16 + lg * 4 + r;
      float sO = bns[oc], bO = bnb[oc], biO = bias[oc];
      #pragma unroll
      for (int ns = 0; ns < 2; ++ns) {
        float val = fmaxf(fmaf(acc[ot][ns][r] + biO, sO, bO), 0.f);
        if (MODE == 0) {
          int u16off = (lg * 4 + r) * 8 + (lr >> 2) * 128 + ns * 4 + (lr & 3);
          BF2 v; v.h[0] = (__bf16)val;
          fbuf[(w * 4 + ot) * 512 + u16off] = (u16)(v.w & 0xFFFF);
        } else {
          int nn = ns * 16 + lr;
          size_t idx = ((size_t)b * C_ + oc) * N_ + n0 + nn;
          outf[idx] = xres[idx] + val;
        }
      }
    }
  }
  if (MODE == 0) {
    __syncthreads();
    #pragma unroll
    for (int rep = 0; rep < 4; ++rep) {
      int f = rep * 4 + (t >> 6);
      size_t dst = (((size_t)b * 128 + nt) * 16 + f) * 512 + (size_t)(t & 63) * 8;
      *(uint4*)(outb + dst) = *(const uint4*)&fbuf[f * 512 + (t & 63) * 8];
    }
  }
}

// ---------------- K-phaseA: fused row stat rmg = max' + log2(sum') ----------------
__global__ __launch_bounds__(512) void k_phaseA(
    const u16* __restrict__ qfm, const u16* __restrict__ kfm,
    const float* __restrict__ qsg, const float* __restrict__ ksg,
    float* __restrict__ rmg) {
  int bid = blockIdx.x;
  bid = (bid & 7) * 64 + (bid >> 3);
  int nt = bid & 127, b = bid >> 7;
  int bN = b * N_;
  int t = threadIdx.x;
  int w = t >> 6, l = t & 63, lr = l & 15, lg = l >> 4;
  int nsub = w & 1, mq = w >> 1;
  int nrow0 = nt * 32 + nsub * 16;

  __shared__ float pM[4][32], pS[4][32];

  const u16* qf_b = qfm + (size_t)b * 131072;
  const u16* kf_b = kfm + (size_t)b * 131072;

  bf16x8 qf = ld_bf8(qf_b + (size_t)(nrow0 >> 4) * 512 + l * 8);
  f32x4 qsv = *(const f32x4*)(qsg + bN + nrow0 + lg * 4);   // already *L2E

  float Mv[4], Sv[4];
  #pragma unroll
  for (int r = 0; r < 4; ++r) { Mv[r] = -3e38f; Sv[r] = 0.f; }

  int mbase = mq * 1024;
  for (int ms = 0; ms < 16; ++ms) {
    float ev[4][4];
    #pragma unroll
    for (int mt2 = 0; mt2 < 4; ++mt2) {
      int m0 = mbase + ms * 64 + mt2 * 16;
      bf16x8 kf = ld_bf8(kf_b + (size_t)(m0 >> 4) * 512 + l * 8);
      f32x4 e = mfma16(qf, kf, f32x4{0.f, 0.f, 0.f, 0.f});
      float ksv = ksg[bN + m0 + lr];
      #pragma unroll
      for (int r = 0; r < 4; ++r) ev[mt2][r] = fmaf(e[r], L2E, -qsv[r] * ksv);  // scaled e'
    }
    #pragma unroll
    for (int r = 0; r < 4; ++r) {
      float t0 = fmaxf(fmaxf(ev[0][r], ev[1][r]), fmaxf(ev[2][r], ev[3][r]));
      float Mn = fmaxf(Mv[r], t0);
      Sv[r] = Sv[r] * __builtin_amdgcn_exp2f(Mv[r] - Mn)
            + __builtin_amdgcn_exp2f(ev[0][r] - Mn)
            + __builtin_amdgcn_exp2f(ev[1][r] - Mn)
            + __builtin_amdgcn_exp2f(ev[2][r] - Mn)
            + __builtin_amdgcn_exp2f(ev[3][r] - Mn);
      Mv[r] = Mn;
    }
  }
  #pragma unroll
  for (int off = 1; off < 16; off <<= 1) {
    #pragma unroll
    for (int r = 0; r < 4; ++r) {
      float Mo = __shfl_xor(Mv[r], off);
      float So = __shfl_xor(Sv[r], off);
      float Mn = fmaxf(Mv[r], Mo);
      Sv[r] = Sv[r] * __builtin_amdgcn_exp2f(Mv[r] - Mn)
            + So   * __builtin_amdgcn_exp2f(Mo   - Mn);
      Mv[r] = Mn;
    }
  }
  if (lr == 0) {
    #pragma unroll
    for (int r = 0; r < 4; ++r) {
      pM[mq][nsub * 16 + lg * 4 + r] = Mv[r];
      pS[mq][nsub * 16 + lg * 4 + r] = Sv[r];
    }
  }
  __syncthreads();
  if (t < 32) {
    float M = fmaxf(fmaxf(pM[0][t], pM[1][t]), fmaxf(pM[2][t], pM[3][t]));
    float S = pS[0][t] * __builtin_amdgcn_exp2f(pM[0][t] - M)
            + pS[1][t] * __builtin_amdgcn_exp2f(pM[1][t] - M)
            + pS[2][t] * __builtin_amdgcn_exp2f(pM[2][t] - M)
            + pS[3][t] * __builtin_amdgcn_exp2f(pM[3][t] - M);
    rmg[bN + nt * 32 + t] = M + __builtin_amdgcn_logf(S);   // v_log_f32 = log2
  }
}

// ---------------- K-phaseB: producer-consumer flash PV (R11 champion, setprio REVERTED) ----------------
// 512 blocks (b, mt128) x 512 thr; 8 waves = (cq4, nh2); wave = m32 x c64 x n-half.
// LDS aliased to 33.8 KB; launch_bounds(512,4) -> VGPR cap 128 (natural 64, R9/R11-proven).
// NOTE (R16 lesson): s_setprio around the consume cluster REGRESSED this kernel 61.6->95.4us
// (lockstep barrier loop has no intra-block role diversity; intrinsic also perturbs regalloc).
__global__ __launch_bounds__(512, 4) void k_phaseB(
    const u16* __restrict__ qfm, const u16* __restrict__ kfm,
    const float* __restrict__ qsg, const float* __restrict__ ksg,
    const float* __restrict__ rmg,
    const u16* __restrict__ vq, const u16* __restrict__ xt,
    u16* __restrict__ diffb) {
  int bid = blockIdx.x;
  bid = (bid & 7) * 64 + (bid >> 3);       // XCD swizzle (512 wgs, bijective)
  int mt = bid & 127, b = bid >> 7;
  int m0 = mt * 32;
  int bN = b * N_;
  int t = threadIdx.x;
  int w = t >> 6, l = t & 63, lr = l & 15, lg = l >> 4;
  int cq = w & 3, nh = w >> 2;
  int c0 = cq * 64;

  // aliased region: pbuf[2][2][4][1024] u16 (32KB, loop) == accl[4][2048] f32 (32KB, epilogue)
  __shared__ __align__(16) char smem[33792];
  u16 (*pbuf)[2][4][1024] = (u16(*)[2][4][1024])smem;
  float (*accl)[2048] = (float(*)[2048])smem;
  float (*csl)[32] = (float(*)[32])(smem + 32768);   // [8][32]

  bf16x8 kf0 = ld_bf8(kfm + (size_t)b * 131072 + (size_t)(mt * 2) * 512 + l * 8);
  bf16x8 kf1 = ld_bf8(kfm + (size_t)b * 131072 + (size_t)(mt * 2 + 1) * 512 + l * 8);
  float ks0 = ksg[bN + m0 + lr];
  float ks1 = ksg[bN + m0 + 16 + lr];

  U16x8 onesu;
  #pragma unroll
  for (int i = 0; i < 8; ++i) onesu.u[i] = 0x3F80;   // bf16 1.0
  bf16x8 ones = onesu.v;

  const u16* qf_b = qfm + (size_t)b * 131072;
  const float* qsb = qsg + bN;
  const float* rmb = rmg + bN;
  const u16* vq_b = vq + (size_t)b * 1048576 + (size_t)(cq * 4) * 512 + (size_t)l * 8;

  f32x4 acc0[4], acc1[4];
  #pragma unroll
  for (int ct = 0; ct < 4; ++ct) {
    acc0[ct] = f32x4{0.f, 0.f, 0.f, 0.f};
    acc1[ct] = f32x4{0.f, 0.f, 0.f, 0.f};
  }
  f32x4 accs0 = f32x4{0.f, 0.f, 0.f, 0.f};
  f32x4 accs1 = f32x4{0.f, 0.f, 0.f, 0.f};

  auto produce = [&](int wd, int buf) {
    bf16x8 qf0 = ld_bf8(qf_b + (size_t)(wd * 2) * 512 + l * 8);
    bf16x8 qf1 = ld_bf8(qf_b + (size_t)(wd * 2 + 1) * 512 + l * 8);
    int nb = wd * 32;
    f32x4 qs0 = *(const f32x4*)(qsb + nb + lg * 4);
    f32x4 qs1 = *(const f32x4*)(qsb + nb + 16 + lg * 4);
    f32x4 rm0 = *(const f32x4*)(rmb + nb + lg * 4);
    f32x4 rm1 = *(const f32x4*)(rmb + nb + 16 + lg * 4);

    f32x4 e00 = mfma16(qf0, kf0, f32x4{0.f, 0.f, 0.f, 0.f});
    f32x4 e01 = mfma16(qf1, kf0, f32x4{0.f, 0.f, 0.f, 0.f});
    f32x4 e10 = mfma16(qf0, kf1, f32x4{0.f, 0.f, 0.f, 0.f});
    f32x4 e11 = mfma16(qf1, kf1, f32x4{0.f, 0.f, 0.f, 0.f});

    float p00[4], p01[4], p10[4], p11[4];
    #pragma unroll
    for (int r = 0; r < 4; ++r) {
      p00[r] = __builtin_amdgcn_exp2f(fmaf(qs0[r], -ks0, fmaf(e00[r], L2E, -rm0[r])));
      p01[r] = __builtin_amdgcn_exp2f(fmaf(qs1[r], -ks0, fmaf(e01[r], L2E, -rm1[r])));
      p10[r] = __builtin_amdgcn_exp2f(fmaf(qs0[r], -ks1, fmaf(e10[r], L2E, -rm0[r])));
      p11[r] = __builtin_amdgcn_exp2f(fmaf(qs1[r], -ks1, fmaf(e11[r], L2E, -rm1[r])));
    }
    U16x8 pb0, pb1;
    #pragma unroll
    for (int r = 0; r < 4; ++r) {
      pb0.h[r] = (__bf16)p00[r]; pb0.h[4 + r] = (__bf16)p01[r];
      pb1.h[r] = (__bf16)p10[r]; pb1.h[4 + r] = (__bf16)p11[r];
    }
    accs0 = mfma16(ones, pb0.v, accs0);    // colsum once per window (matrix pipe)
    accs1 = mfma16(ones, pb1.v, accs1);
    u16* dst = &pbuf[nh][buf][cq][0];
    *(uint4*)&dst[l * 8] = pb0.q;
    *(uint4*)&dst[512 + l * 8] = pb1.q;
  };

  int wbase = nh * 64;
  produce(wbase + cq, 0);
  BAR();

  for (int g = 0; g < 16; ++g) {
    if (g < 15) produce(wbase + (g + 1) * 4 + cq, (g + 1) & 1);
    int gbuf = g & 1;
    #pragma unroll
    for (int j = 0; j < 4; ++j) {
      int wd = wbase + g * 4 + j;
      const u16* src = &pbuf[nh][gbuf][j][0];
      U16x8 pb0, pb1;
      pb0.q = *(const uint4*)&src[l * 8];
      pb1.q = *(const uint4*)&src[512 + l * 8];
      const u16* vp = vq_b + (size_t)wd * 8192;
      U16x8 v0, v1, v2, v3;
      v0.q = *(const uint4*)(vp);
      v1.q = *(const uint4*)(vp + 512);
      v2.q = *(const uint4*)(vp + 1024);
      v3.q = *(const uint4*)(vp + 1536);
      acc0[0] = mfma16(v0.v, pb0.v, acc0[0]);
      acc1[0] = mfma16(v0.v, pb1.v, acc1[0]);
      acc0[1] = mfma16(v1.v, pb0.v, acc0[1]);
      acc1[1] = mfma16(v1.v, pb1.v, acc1[1]);
      acc0[2] = mfma16(v2.v, pb0.v, acc0[2]);
      acc1[2] = mfma16(v2.v, pb1.v, acc1[2]);
      acc0[3] = mfma16(v3.v, pb0.v, acc0[3]);
      acc1[3] = mfma16(v3.v, pb1.v, acc1[3]);
    }
    BAR();   // produce(g+1) visible; consume(g) drained -> buf reusable at g+2; pbuf free after g=15
  }

  // colsum publish (each produced window counted once; sum all 8 waves)
  if (lg == 0) { csl[w][lr] = accs0[0]; csl[w][16 + lr] = accs1[0]; }
  // accl ALIASES pbuf: safe — final BAR drained every wave's last pbuf read
  if (nh == 1) {
    #pragma unroll
    for (int ct = 0; ct < 4; ++ct) {
      *(f32x4*)&accl[cq][(ct * 2 + 0) * 256 + l * 4] = acc0[ct];
      *(f32x4*)&accl[cq][(ct * 2 + 1) * 256 + l * 4] = acc1[ct];
    }
  }
  __syncthreads();
  if (nh == 0) {
    #pragma unroll
    for (int ct = 0; ct < 4; ++ct) {
      acc0[ct] += *(const f32x4*)&accl[cq][(ct * 2 + 0) * 256 + l * 4];
      acc1[ct] += *(const f32x4*)&accl[cq][(ct * 2 + 1) * 256 + l * 4];
    }
    float s0 = 0.f, s1 = 0.f;
    #pragma unroll
    for (int i = 0; i < 8; ++i) { s0 += csl[i][lr]; s1 += csl[i][16 + lr]; }
    float inv0 = __builtin_amdgcn_rcpf(1e-9f + s0);
    float inv1 = __builtin_amdgcn_rcpf(1e-9f + s1);

    // epilogue: diff = x - acc*inv, bf16 [b][n][c]
    #pragma unroll
    for (int ct = 0; ct < 4; ++ct) {
      {
        size_t base = ((size_t)(bN + m0 + lr)) * C_ + c0 + ct * 16 + lg * 4;
        uint2 xv2 = *(const uint2*)(xt + base);
        BF2 xa, xb; xa.w = xv2.x; xb.w = xv2.y;
        BF2 o0, o1;
        o0.h[0] = (__bf16)((float)xa.h[0] - acc0[ct][0] * inv0);
        o0.h[1] = (__bf16)((float)xa.h[1] - acc0[ct][1] * inv0);
        o1.h[0] = (__bf16)((float)xb.h[0] - acc0[ct][2] * inv0);
        o1.h[1] = (__bf16)((float)xb.h[1] - acc0[ct][3] * inv0);
        uint2 ov; ov.x = o0.w; ov.y = o1.w;
        *(uint2*)(diffb + base) = ov;
      }
      {
        size_t base = ((size_t)(bN + m0 + 16 + lr)) * C_ + c0 + ct * 16 + lg * 4;
        uint2 xv2 = *(const uint2*)(xt + base);
        BF2 xa, xb; xa.w = xv2.x; xb.w = xv2.y;
        BF2 o0, o1;
        o0.h[0] = (__bf16)((float)xa.h[0] - acc1[ct][0] * inv1);
        o0.h[1] = (__bf16)((float)xa.h[1] - acc1[ct][1] * inv1);
        o1.h[0] = (__bf16)((float)xb.h[0] - acc1[ct][2] * inv1);
        o1.h[1] = (__bf16)((float)xb.h[1] - acc1[ct][3] * inv1);
        uint2 ov; ov.x = o0.w; ov.y = o1.w;
        *(uint2*)(diffb + base) = ov;
      }
    }
  }
}

// ---------------- launch ----------------
extern "C" void kernel_launch(void* const* d_in, const int* in_sizes, int n_in,
                              void* d_out, int out_size, void* d_ws, size_t ws_size,
                              hipStream_t stream) {
  const float* x       = (const float*)d_in[0];
  const float* qk_w    = (const float*)d_in[1];
  const float* v_w     = (const float*)d_in[2];
  const float* v_b     = (const float*)d_in[3];
  const float* trans_w = (const float*)d_in[4];
  const float* trans_b = (const float*)d_in[5];
  const float* bn1s = (const float*)d_in[6];
  const float* bn1b = (const float*)d_in[7];
  const float* bn2s = (const float*)d_in[8];
  const float* bn2b = (const float*)d_in[9];
  const float* bn3s = (const float*)d_in[10];
  const float* bn3b = (const float*)d_in[11];
  const float* ans  = (const float*)d_in[12];
  const float* anb  = (const float*)d_in[13];
  float* out = (float*)d_out;
  char* ws = (char*)d_ws;

  if (ws_size < 27820032) return;

  u16*   xt    = (u16*)(ws + 0);          // [B][N][C] bf16   8 MB
  u16*   vq    = (u16*)(ws + 8388608);    // V fragment-major 8 MB
  u16*   diffb = (u16*)(ws + 16777216);   // [B][N][C] bf16   8 MB
  u16*   qfm   = (u16*)(ws + 25165824);   // q frags 1 MB
  u16*   kfm   = (u16*)(ws + 26214400);   // k frags 1 MB
  u16*   wvf   = (u16*)(ws + 27262976);   // v-weights fragment-major
  u16*   wtf   = (u16*)(ws + 27394048);   // t-weights fragment-major
  float* wqkt  = (float*)(ws + 27525120);
  float* qsg   = (float*)(ws + 27557888);
  float* ksg   = (float*)(ws + 27623424);
  float* rmg   = (float*)(ws + 27688960);

  k_xt<<<1024, 256, 0, stream>>>(x, xt, v_w, trans_w, qk_w, wvf, wtf, wqkt);
  k_qk<<<256, 256, 0, stream>>>(x, wqkt, bn1s, bn1b, bn2s, bn2b, qfm, kfm, qsg, ksg);
  k_gemm256<0><<<512, 256, 0, stream>>>(wvf, xt, v_b, bn3s, bn3b, nullptr, vq, nullptr);
  k_phaseA<<<512, 512, 0, stream>>>(qfm, kfm, qsg, ksg, rmg);
  k_phaseB<<<512, 512, 0, stream>>>(qfm, kfm, qsg, ksg, rmg, vq, xt, diffb);
  k_gemm256<1><<<512, 256, 0, stream>>>(wtf, diffb, trans_b, ans, anb, x, nullptr, out);
}